// Round 7
// baseline (656.016 us; speedup 1.0000x reference)
//
#include <hip/hip_runtime.h>
#include <hip/hip_bf16.h>

typedef unsigned short u16;
typedef __attribute__((ext_vector_type(8))) short short8;   // 8 x bf16 (4 VGPR)
typedef __attribute__((ext_vector_type(4))) short s16x4;
typedef __attribute__((ext_vector_type(4))) float f32x4;

#define T_SEQ  4096
#define HEADS  16
#define HDIM   64
#define CDIM   1024
#define MDIM   8192              // B*T
#define HSZ    (T_SEQ * HDIM)    // elems per (b,h) head-plane
#define SEC    8388608           // elems per qkv section = B*T*C

__device__ __forceinline__ u16 f2bf(float f) {
    __hip_bfloat16 h = __float2bfloat16(f);
    u16 u; __builtin_memcpy(&u, &h, 2);
    return u;
}
__device__ __forceinline__ float bf2f(u16 u) {
    unsigned int x = ((unsigned int)u) << 16;
    float f; __builtin_memcpy(&f, &x, 4);
    return f;
}

// ---------------------------------------------------------------------------
// fp32 -> bf16 cast, 4 elems/thread.
// ---------------------------------------------------------------------------
__global__ __launch_bounds__(256) void cast_k(const float* __restrict__ in,
                                              u16* __restrict__ out, int n4) {
    const int i = blockIdx.x * 256 + threadIdx.x;
    if (i < n4) {
        f32x4 v = ((const f32x4*)in)[i];
        s16x4 o;
        #pragma unroll
        for (int j = 0; j < 4; ++j) o[j] = (short)f2bf(v[j]);
        ((s16x4*)out)[i] = o;
    }
}

// ---------------------------------------------------------------------------
// Batched transpose: out[z][c][r] = (bf16)in[z][r][c].  R,C multiples of 32.
// IN_F32: input fp32 (weights, fp32 v-sections) vs bf16.
// grid (C/32, R/32, Z), block (32,8)
// ---------------------------------------------------------------------------
template <int IN_F32>
__global__ __launch_bounds__(256) void transpose_k(const void* __restrict__ in_,
                                                   u16* __restrict__ out,
                                                   int R, int C) {
    __shared__ u16 tile[32][33];
    const size_t zoff = (size_t)blockIdx.z * R * C;
    const int c0 = blockIdx.x * 32, r0 = blockIdx.y * 32;
    const int tx = threadIdx.x, ty = threadIdx.y;
    #pragma unroll
    for (int i = ty; i < 32; i += 8) {
        const size_t idx = zoff + (size_t)(r0 + i) * C + c0 + tx;
        tile[i][tx] = IN_F32 ? f2bf(((const float*)in_)[idx])
                             : ((const u16*)in_)[idx];
    }
    __syncthreads();
    #pragma unroll
    for (int i = ty; i < 32; i += 8)
        out[zoff + (size_t)(c0 + i) * R + r0 + tx] = tile[tx][i];
}

// ---------------------------------------------------------------------------
// bf16 GEMM: C[m][n] = sum_k A[m][k] * Bt[n][k] + bias[n]   (bias fp32)
//   128x128 tile, BK=64, 4 waves (2x2), 16x16x32 MFMA, XOR-swizzled LDS.
// MODE 0: qkv epilogue -> q->qws (bf16, B,H,T,HD); k/v -> outp (FP32, head
//         layout at +SEC / +2*SEC)
// MODE 1: proj epilogue -> y row-major (MDIM x CDIM) FP32 into outp
// grid (N/128, MDIM/128), block 256
// ---------------------------------------------------------------------------
template <int MODE>
__global__ __launch_bounds__(256) void gemm_k(const u16* __restrict__ A,
                                              const u16* __restrict__ Bt,
                                              const float* __restrict__ bias,
                                              float* __restrict__ outp,
                                              u16* __restrict__ qws, int K) {
    __shared__ unsigned char sA[16384];   // [128 rows][64 k] bf16, 128B rows
    __shared__ unsigned char sB[16384];
    const int tid  = threadIdx.x;
    const int lane = tid & 63;
    const int w = tid >> 6, wr = w >> 1, wc = w & 1;
    const int m0 = blockIdx.y * 128, n0 = blockIdx.x * 128;
    const int fr = lane & 15, fg = lane >> 4;

    f32x4 acc[4][4] = {};

    const int srow  = tid >> 1;
    const int scolb = (tid & 1) * 64;            // byte offset of half-row
    const u16* ga = A  + (size_t)(m0 + srow) * K + (tid & 1) * 32;
    const u16* gb = Bt + (size_t)(n0 + srow) * K + (tid & 1) * 32;
    unsigned char* wAr = sA + srow * 128;
    unsigned char* wBr = sB + srow * 128;
    const int swz  = (srow & 7) << 4;            // write swizzle
    const int rswz = (fr & 7) << 4;              // read swizzle (row = ..+fr)

    const int nk = K >> 6;
    for (int kt = 0; kt < nk; ++kt) {
        short8 va0 = *(const short8*)(ga + 0);
        short8 va1 = *(const short8*)(ga + 8);
        short8 va2 = *(const short8*)(ga + 16);
        short8 va3 = *(const short8*)(ga + 24);
        short8 vb0 = *(const short8*)(gb + 0);
        short8 vb1 = *(const short8*)(gb + 8);
        short8 vb2 = *(const short8*)(gb + 16);
        short8 vb3 = *(const short8*)(gb + 24);
        ga += 64; gb += 64;
        __syncthreads();
        *(short8*)(wAr + ((scolb +  0) ^ swz)) = va0;
        *(short8*)(wAr + ((scolb + 16) ^ swz)) = va1;
        *(short8*)(wAr + ((scolb + 32) ^ swz)) = va2;
        *(short8*)(wAr + ((scolb + 48) ^ swz)) = va3;
        *(short8*)(wBr + ((scolb +  0) ^ swz)) = vb0;
        *(short8*)(wBr + ((scolb + 16) ^ swz)) = vb1;
        *(short8*)(wBr + ((scolb + 32) ^ swz)) = vb2;
        *(short8*)(wBr + ((scolb + 48) ^ swz)) = vb3;
        __syncthreads();
        #pragma unroll
        for (int kk = 0; kk < 2; ++kk) {
            short8 af[4], bf[4];
            #pragma unroll
            for (int m = 0; m < 4; ++m)
                af[m] = *(const short8*)(sA + (wr*64 + m*16 + fr) * 128 +
                                         ((kk*64 + fg*16) ^ rswz));
            #pragma unroll
            for (int n = 0; n < 4; ++n)
                bf[n] = *(const short8*)(sB + (wc*64 + n*16 + fr) * 128 +
                                         ((kk*64 + fg*16) ^ rswz));
            #pragma unroll
            for (int m = 0; m < 4; ++m)
                #pragma unroll
                for (int n = 0; n < 4; ++n)
                    acc[m][n] = __builtin_amdgcn_mfma_f32_16x16x32_bf16(
                        af[m], bf[n], acc[m][n], 0, 0, 0);
        }
    }

    // epilogue: C/D layout col = lane&15, row = (lane>>4)*4 + reg  [m89]
    #pragma unroll
    for (int n = 0; n < 4; ++n) {
        const int gn = n0 + wc*64 + n*16 + fr;
        const float bn = bias[gn];
        if (MODE == 0) {
            const int s = gn >> 10;               // 0=q 1=k 2=v
            const int c = gn & 1023;
            const int h = c >> 6, d = c & 63;
            if (s == 0) {
                #pragma unroll
                for (int m = 0; m < 4; ++m)
                    #pragma unroll
                    for (int r = 0; r < 4; ++r) {
                        const int gm = m0 + wr*64 + m*16 + fg*4 + r;
                        const int b = gm >> 12, t = gm & 4095;
                        qws[(size_t)((b << 4) + h) * HSZ + (size_t)t * HDIM + d] =
                            f2bf(acc[m][n][r] + bn);
                    }
            } else {
                float* fdst = outp + (size_t)s * SEC;   // k or v section, FP32
                #pragma unroll
                for (int m = 0; m < 4; ++m)
                    #pragma unroll
                    for (int r = 0; r < 4; ++r) {
                        const int gm = m0 + wr*64 + m*16 + fg*4 + r;
                        const int b = gm >> 12, t = gm & 4095;
                        fdst[(size_t)((b << 4) + h) * HSZ + (size_t)t * HDIM + d] =
                            acc[m][n][r] + bn;
                    }
            }
        } else {
            #pragma unroll
            for (int m = 0; m < 4; ++m)
                #pragma unroll
                for (int r = 0; r < 4; ++r) {
                    const int gm = m0 + wr*64 + m*16 + fg*4 + r;
                    outp[(size_t)gm * CDIM + gn] = acc[m][n][r] + bn;   // FP32 y
                }
        }
    }
}

// ---------------------------------------------------------------------------
// Flash attention fwd (causal), bf16 MFMA, fp32 accum.
//   q: (BH,T,64) bf16   k: (BH,T,64) FP32 (d_out section)   vt: (BH,64,T) bf16
//   att out: (B, T, H*64) bf16 (internal ws buffer)
// grid (T/64, BH), block 256. 4 waves x 16 q-rows. Online softmax.
// ---------------------------------------------------------------------------
__global__ __launch_bounds__(256) void attn_k(const u16* __restrict__ q,
                                              const float* __restrict__ kk_,
                                              const u16* __restrict__ vt,
                                              u16* __restrict__ att) {
    __shared__ unsigned char sK[4096];   // [32 key][64 d]  128B rows
    __shared__ unsigned char sV[4096];   // [64 d][32 key]  64B rows (V^T tile)
    __shared__ unsigned char sP[4096];   // per-wave [16 q][32 key] 1KB each
    const int qblk = blockIdx.x, bh = blockIdx.y;
    const int tid = threadIdx.x, lane = tid & 63, w = tid >> 6;
    const int fr = lane & 15, fg = lane >> 4;
    const size_t hbase = (size_t)bh * HSZ;
    const int q0 = qblk * 64 + w * 16;

    short8 qf0 = *(const short8*)(q + hbase + (size_t)(q0 + fr) * 64 + fg * 8);
    short8 qf1 = *(const short8*)(q + hbase + (size_t)(q0 + fr) * 64 + 32 + fg * 8);

    f32x4 o[4] = {};
    float mrow[4] = {-1e30f, -1e30f, -1e30f, -1e30f};
    float lrow[4] = {0.f, 0.f, 0.f, 0.f};

    const int krow = tid >> 3, kcolb = (tid & 7) * 16;
    const int swzK = (krow & 7) << 4;
    const int vrow = tid >> 2, vcolb = (tid & 3) * 16;
    const int swzV = (vrow & 3) << 4;
    const int rswzK = (fr & 7) << 4;
    const int rswzV = (fr & 3) << 4;

    const float* gk = kk_ + hbase + (size_t)krow * 64 + (tid & 7) * 8;  // FP32
    const u16*   gv = vt  + hbase + (size_t)vrow * T_SEQ + (tid & 3) * 8;

    const int nkt = (qblk * 64 + 64) >> 5;
    for (int kt = 0; kt < nkt; ++kt) {
        f32x4 ka = *(const f32x4*)(gk + (size_t)kt * 2048);      // 32 rows * 64
        f32x4 kb = *(const f32x4*)(gk + (size_t)kt * 2048 + 4);
        short8 kv;
        #pragma unroll
        for (int j = 0; j < 4; ++j) {
            kv[j]     = (short)f2bf(ka[j]);
            kv[4 + j] = (short)f2bf(kb[j]);
        }
        short8 vv = *(const short8*)(gv + kt * 32);
        __syncthreads();
        *(short8*)(sK + krow * 128 + (kcolb ^ swzK)) = kv;
        *(short8*)(sV + vrow * 64  + (vcolb ^ swzV)) = vv;
        __syncthreads();

        // S = Q K^T (16 q x 32 key), two 16-key halves
        f32x4 sc[2];
        #pragma unroll
        for (int kh = 0; kh < 2; ++kh) {
            short8 kf0 = *(const short8*)(sK + (kh*16 + fr) * 128 +
                                          ((fg*16) ^ rswzK));
            short8 kf1 = *(const short8*)(sK + (kh*16 + fr) * 128 +
                                          ((64 + fg*16) ^ rswzK));
            f32x4 z = {0.f, 0.f, 0.f, 0.f};
            z = __builtin_amdgcn_mfma_f32_16x16x32_bf16(qf0, kf0, z, 0, 0, 0);
            z = __builtin_amdgcn_mfma_f32_16x16x32_bf16(qf1, kf1, z, 0, 0, 0);
            sc[kh] = z;
        }

        const int kb2 = kt * 32;
        #pragma unroll
        for (int r = 0; r < 4; ++r) {
            const int qg = q0 + fg * 4 + r;
            #pragma unroll
            for (int kh = 0; kh < 2; ++kh) {
                const int kgi = kb2 + kh * 16 + fr;
                sc[kh][r] = (kgi <= qg) ? sc[kh][r] * 0.125f : -1e30f;
            }
            float mx = fmaxf(sc[0][r], sc[1][r]);
            mx = fmaxf(mx, __shfl_xor(mx, 1, 64));
            mx = fmaxf(mx, __shfl_xor(mx, 2, 64));
            mx = fmaxf(mx, __shfl_xor(mx, 4, 64));
            mx = fmaxf(mx, __shfl_xor(mx, 8, 64));
            const float mn = fmaxf(mrow[r], mx);
            const float p0 = __expf(sc[0][r] - mn);
            const float p1 = __expf(sc[1][r] - mn);
            float rs = p0 + p1;
            rs += __shfl_xor(rs, 1, 64);
            rs += __shfl_xor(rs, 2, 64);
            rs += __shfl_xor(rs, 4, 64);
            rs += __shfl_xor(rs, 8, 64);
            const float sf = __expf(mrow[r] - mn);
            lrow[r] = lrow[r] * sf + rs;
            mrow[r] = mn;
            #pragma unroll
            for (int db = 0; db < 4; ++db) o[db][r] *= sf;
            const int prow = fg * 4 + r;     // prow&3 == r
            *(u16*)(sP + w*1024 + prow*64 + ((fr*2)      ^ (r << 4))) = f2bf(p0);
            *(u16*)(sP + w*1024 + prow*64 + ((32 + fr*2) ^ (r << 4))) = f2bf(p1);
        }

        // barrier: scalar u16 sP stores vs short8 vector reload below
        __syncthreads();

        short8 pf = *(const short8*)(sP + w*1024 + fr*64 + ((fg*16) ^ rswzV));
        #pragma unroll
        for (int db = 0; db < 4; ++db) {
            short8 vf = *(const short8*)(sV + (db*16 + fr) * 64 +
                                         ((fg*16) ^ rswzV));
            o[db] = __builtin_amdgcn_mfma_f32_16x16x32_bf16(pf, vf, o[db], 0, 0, 0);
        }
    }

    const int b = bh >> 4, h = bh & 15;
    #pragma unroll
    for (int db = 0; db < 4; ++db)
        #pragma unroll
        for (int r = 0; r < 4; ++r) {
            const int t = q0 + fg * 4 + r;
            att[(size_t)(b * T_SEQ + t) * CDIM + h * 64 + db * 16 + fr] =
                f2bf(o[db][r] / lrow[r]);
        }
}

// ---------------------------------------------------------------------------
// Orchestration. Inputs fp32 (identified by size), OUTPUTS FP32 (y,k,v).
// Workspace (48 MiB, overlapped):
//   [ 0,16M)  q_ws bf16 (B,H,T,64);  wTp overlays after attn
//   [16,32M)  x_bf (pre-gemm0) -> vT bf16 (B,H,64,T) after gemm0
//   [32,48M)  wTa (3072x1024, pre-gemm0) -> attb bf16 (B,T,C) after gemm0
// ---------------------------------------------------------------------------
extern "C" void kernel_launch(void* const* d_in, const int* in_sizes, int n_in,
                              void* d_out, int out_size, void* d_ws, size_t ws_size,
                              hipStream_t stream) {
    (void)out_size; (void)ws_size;
    const float *x = nullptr, *w_attn = nullptr, *b_attn = nullptr,
                *w_proj = nullptr, *b_proj = nullptr;
    for (int i = 0; i < n_in; ++i) {
        switch (in_sizes[i]) {
            case 8388608: x      = (const float*)d_in[i]; break;
            case 3145728: w_attn = (const float*)d_in[i]; break;
            case 3072:    b_attn = (const float*)d_in[i]; break;
            case 1048576: w_proj = (const float*)d_in[i]; break;
            case 1024:    b_proj = (const float*)d_in[i]; break;
        }
    }
    if (!x || !w_attn || !b_attn || !w_proj || !b_proj) return;

    float* out = (float*)d_out;              // *** FP32 output buffer ***
    unsigned char* ws = (unsigned char*)d_ws;

    u16* q_ws = (u16*)(ws);
    u16* wTp  = (u16*)(ws);              // overlays q_ws (dead after attn)
    u16* x_bf = (u16*)(ws + 16777216);
    u16* vT   = (u16*)(ws + 16777216);   // overlays x_bf (dead after gemm0)
    u16* wTa  = (u16*)(ws + 33554432);
    u16* attb = (u16*)(ws + 33554432);   // overlays wTa (dead after gemm0)

    // x (fp32) -> x_bf
    cast_k<<<8192, 256, 0, stream>>>(x, x_bf, 2097152);
    // w_attn (1024x3072 fp32) -> wTa (3072x1024 bf16)
    transpose_k<1><<<dim3(96, 32, 1), dim3(32, 8), 0, stream>>>(w_attn, wTa, 1024, 3072);
    // qkv gemm: q -> q_ws (bf16), k -> out+SEC (fp32), v -> out+2SEC (fp32)
    gemm_k<0><<<dim3(24, 64), 256, 0, stream>>>(x_bf, wTa, b_attn, out, q_ws, 1024);
    // v fp32 (BH,4096,64) -> vT bf16 (BH,64,4096)
    transpose_k<1><<<dim3(2, 128, 32), dim3(32, 8), 0, stream>>>(out + 2 * (size_t)SEC, vT, 4096, 64);
    // flash attention -> attb bf16 (B,T,C)
    attn_k<<<dim3(64, 32), 256, 0, stream>>>(q_ws, out + SEC, vT, attb);
    // w_proj (1024x1024 fp32) -> wTp bf16
    transpose_k<1><<<dim3(32, 32, 1), dim3(32, 8), 0, stream>>>(w_proj, wTp, 1024, 1024);
    // proj gemm -> y fp32 at out[0:SEC)
    gemm_k<1><<<dim3(8, 64), 256, 0, stream>>>(attb, wTp, b_proj, out, nullptr, 1024);
}

// Round 8
// 402.168 us; speedup vs baseline: 1.6312x; 1.6312x over previous
//
#include <hip/hip_runtime.h>
#include <hip/hip_bf16.h>

typedef unsigned short u16;
typedef __attribute__((ext_vector_type(8))) short short8;   // 8 x bf16 (4 VGPR)
typedef __attribute__((ext_vector_type(4))) short s16x4;
typedef __attribute__((ext_vector_type(4))) float f32x4;

#define T_SEQ  4096
#define HEADS  16
#define HDIM   64
#define CDIM   1024
#define MDIM   8192              // B*T
#define HSZ    (T_SEQ * HDIM)    // elems per (b,h) head-plane
#define SEC    8388608           // elems per qkv section = B*T*C

__device__ __forceinline__ u16 f2bf(float f) {
    __hip_bfloat16 h = __float2bfloat16(f);
    u16 u; __builtin_memcpy(&u, &h, 2);
    return u;
}
__device__ __forceinline__ float bf2f(u16 u) {
    unsigned int x = ((unsigned int)u) << 16;
    float f; __builtin_memcpy(&f, &x, 4);
    return f;
}

// ---------------------------------------------------------------------------
// fp32 -> bf16 cast, 4 elems/thread.
// ---------------------------------------------------------------------------
__global__ __launch_bounds__(256) void cast_k(const float* __restrict__ in,
                                              u16* __restrict__ out, int n4) {
    const int i = blockIdx.x * 256 + threadIdx.x;
    if (i < n4) {
        f32x4 v = ((const f32x4*)in)[i];
        s16x4 o;
        #pragma unroll
        for (int j = 0; j < 4; ++j) o[j] = (short)f2bf(v[j]);
        ((s16x4*)out)[i] = o;
    }
}

// ---------------------------------------------------------------------------
// Batched transpose: out[z][c][r] = (bf16)in[z][r][c].  R,C multiples of 32.
// grid (C/32, R/32, Z), block (32,8)
// ---------------------------------------------------------------------------
template <int IN_F32>
__global__ __launch_bounds__(256) void transpose_k(const void* __restrict__ in_,
                                                   u16* __restrict__ out,
                                                   int R, int C) {
    __shared__ u16 tile[32][33];
    const size_t zoff = (size_t)blockIdx.z * R * C;
    const int c0 = blockIdx.x * 32, r0 = blockIdx.y * 32;
    const int tx = threadIdx.x, ty = threadIdx.y;
    #pragma unroll
    for (int i = ty; i < 32; i += 8) {
        const size_t idx = zoff + (size_t)(r0 + i) * C + c0 + tx;
        tile[i][tx] = IN_F32 ? f2bf(((const float*)in_)[idx])
                             : ((const u16*)in_)[idx];
    }
    __syncthreads();
    #pragma unroll
    for (int i = ty; i < 32; i += 8)
        out[zoff + (size_t)(c0 + i) * R + r0 + tx] = tile[tx][i];
}

// ---------------------------------------------------------------------------
// bf16 GEMM: C[m][n] = sum_k A[m][k] * Bt[n][k] + bias[n]   (bias fp32)
//   128x128 tile, BK=64, 4 waves (2x2), 16x16x32 MFMA, XOR-swizzled LDS.
// MODE 0: qkv epilogue -> q->qws (bf16); k/v -> outp fp32 head layout
// MODE 1: proj epilogue -> y row-major fp32
// grid (N/128, MDIM/128), block 256
// ---------------------------------------------------------------------------
template <int MODE>
__global__ __launch_bounds__(256) void gemm_k(const u16* __restrict__ A,
                                              const u16* __restrict__ Bt,
                                              const float* __restrict__ bias,
                                              float* __restrict__ outp,
                                              u16* __restrict__ qws, int K) {
    __shared__ unsigned char sA[16384];   // [128 rows][64 k] bf16, 128B rows
    __shared__ unsigned char sB[16384];
    const int tid  = threadIdx.x;
    const int lane = tid & 63;
    const int w = tid >> 6, wr = w >> 1, wc = w & 1;
    const int m0 = blockIdx.y * 128, n0 = blockIdx.x * 128;
    const int fr = lane & 15, fg = lane >> 4;

    f32x4 acc[4][4] = {};

    const int srow  = tid >> 1;
    const int scolb = (tid & 1) * 64;
    const u16* ga = A  + (size_t)(m0 + srow) * K + (tid & 1) * 32;
    const u16* gb = Bt + (size_t)(n0 + srow) * K + (tid & 1) * 32;
    unsigned char* wAr = sA + srow * 128;
    unsigned char* wBr = sB + srow * 128;
    const int swz  = (srow & 7) << 4;
    const int rswz = (fr & 7) << 4;

    const int nk = K >> 6;
    for (int kt = 0; kt < nk; ++kt) {
        short8 va0 = *(const short8*)(ga + 0);
        short8 va1 = *(const short8*)(ga + 8);
        short8 va2 = *(const short8*)(ga + 16);
        short8 va3 = *(const short8*)(ga + 24);
        short8 vb0 = *(const short8*)(gb + 0);
        short8 vb1 = *(const short8*)(gb + 8);
        short8 vb2 = *(const short8*)(gb + 16);
        short8 vb3 = *(const short8*)(gb + 24);
        ga += 64; gb += 64;
        __syncthreads();
        *(short8*)(wAr + ((scolb +  0) ^ swz)) = va0;
        *(short8*)(wAr + ((scolb + 16) ^ swz)) = va1;
        *(short8*)(wAr + ((scolb + 32) ^ swz)) = va2;
        *(short8*)(wAr + ((scolb + 48) ^ swz)) = va3;
        *(short8*)(wBr + ((scolb +  0) ^ swz)) = vb0;
        *(short8*)(wBr + ((scolb + 16) ^ swz)) = vb1;
        *(short8*)(wBr + ((scolb + 32) ^ swz)) = vb2;
        *(short8*)(wBr + ((scolb + 48) ^ swz)) = vb3;
        __syncthreads();
        #pragma unroll
        for (int kk = 0; kk < 2; ++kk) {
            short8 af[4], bf[4];
            #pragma unroll
            for (int m = 0; m < 4; ++m)
                af[m] = *(const short8*)(sA + (wr*64 + m*16 + fr) * 128 +
                                         ((kk*64 + fg*16) ^ rswz));
            #pragma unroll
            for (int n = 0; n < 4; ++n)
                bf[n] = *(const short8*)(sB + (wc*64 + n*16 + fr) * 128 +
                                         ((kk*64 + fg*16) ^ rswz));
            #pragma unroll
            for (int m = 0; m < 4; ++m)
                #pragma unroll
                for (int n = 0; n < 4; ++n)
                    acc[m][n] = __builtin_amdgcn_mfma_f32_16x16x32_bf16(
                        af[m], bf[n], acc[m][n], 0, 0, 0);
        }
    }

    // epilogue: C/D layout col = lane&15, row = (lane>>4)*4 + reg  [m89]
    #pragma unroll
    for (int n = 0; n < 4; ++n) {
        const int gn = n0 + wc*64 + n*16 + fr;
        const float bn = bias[gn];
        if (MODE == 0) {
            const int s = gn >> 10;               // 0=q 1=k 2=v
            const int c = gn & 1023;
            const int h = c >> 6, d = c & 63;
            if (s == 0) {
                #pragma unroll
                for (int m = 0; m < 4; ++m)
                    #pragma unroll
                    for (int r = 0; r < 4; ++r) {
                        const int gm = m0 + wr*64 + m*16 + fg*4 + r;
                        const int b = gm >> 12, t = gm & 4095;
                        qws[(size_t)((b << 4) + h) * HSZ + (size_t)t * HDIM + d] =
                            f2bf(acc[m][n][r] + bn);
                    }
            } else {
                float* fdst = outp + (size_t)s * SEC;
                #pragma unroll
                for (int m = 0; m < 4; ++m)
                    #pragma unroll
                    for (int r = 0; r < 4; ++r) {
                        const int gm = m0 + wr*64 + m*16 + fg*4 + r;
                        const int b = gm >> 12, t = gm & 4095;
                        fdst[(size_t)((b << 4) + h) * HSZ + (size_t)t * HDIM + d] =
                            acc[m][n][r] + bn;
                    }
            }
        } else {
            #pragma unroll
            for (int m = 0; m < 4; ++m)
                #pragma unroll
                for (int r = 0; r < 4; ++r) {
                    const int gm = m0 + wr*64 + m*16 + fg*4 + r;
                    outp[(size_t)gm * CDIM + gn] = acc[m][n][r] + bn;
                }
        }
    }
}

// ---------------------------------------------------------------------------
// Flash attention fwd (causal), bf16 MFMA, fp32 accum, CAUSAL-BALANCED.
//   Block pair = blockIdx.x processes qblk {pair, 63-pair}: 130 tiles each.
//   q: (BH,T,64) bf16   k: (BH,T,64) fp32   vt: (BH,64,T) bf16
//   att out: (B, T, H*64) bf16
// grid (32, BH), block 256. 4 waves x 16 q-rows per qblk phase.
// ---------------------------------------------------------------------------
__global__ __launch_bounds__(256) void attn_k(const u16* __restrict__ q,
                                              const float* __restrict__ kk_,
                                              const u16* __restrict__ vt,
                                              u16* __restrict__ att) {
    __shared__ unsigned char sK[4096];   // [32 key][64 d]  128B rows
    __shared__ unsigned char sV[4096];   // [64 d][32 key]  64B rows (V^T tile)
    __shared__ unsigned char sP[4096];   // per-wave [16 q][32 key] 1KB each
    const int pair = blockIdx.x, bh = blockIdx.y;
    const int tid = threadIdx.x, lane = tid & 63, w = tid >> 6;
    const int fr = lane & 15, fg = lane >> 4;
    const size_t hbase = (size_t)bh * HSZ;

    const int krow = tid >> 3, kcolb = (tid & 7) * 16;
    const int swzK = (krow & 7) << 4;
    const int vrow = tid >> 2, vcolb = (tid & 3) * 16;
    const int swzV = (vrow & 3) << 4;
    const int rswzK = (fr & 7) << 4;
    const int rswzV = (fr & 3) << 4;

    const float* gk = kk_ + hbase + (size_t)krow * 64 + (tid & 7) * 8;  // fp32
    const u16*   gv = vt  + hbase + (size_t)vrow * T_SEQ + (tid & 3) * 8;
    const int b = bh >> 4, h = bh & 15;

    #pragma unroll
    for (int ph = 0; ph < 2; ++ph) {
        const int qblk = ph ? 63 - pair : pair;
        const int q0 = qblk * 64 + w * 16;

        short8 qf0 = *(const short8*)(q + hbase + (size_t)(q0 + fr) * 64 + fg * 8);
        short8 qf1 = *(const short8*)(q + hbase + (size_t)(q0 + fr) * 64 + 32 + fg * 8);

        f32x4 o[4] = {};
        float mrow[4] = {-1e30f, -1e30f, -1e30f, -1e30f};
        float srow[4] = {0.f, 0.f, 0.f, 0.f};   // per-lane partial sums

        const int nkt = 2 * (qblk + 1);
        for (int kt = 0; kt < nkt; ++kt) {
            f32x4 ka = *(const f32x4*)(gk + (size_t)kt * 2048);
            f32x4 kb = *(const f32x4*)(gk + (size_t)kt * 2048 + 4);
            short8 kv;
            #pragma unroll
            for (int j = 0; j < 4; ++j) {
                kv[j]     = (short)f2bf(ka[j]);
                kv[4 + j] = (short)f2bf(kb[j]);
            }
            short8 vv = *(const short8*)(gv + kt * 32);
            __syncthreads();   // also orders phase0 LDS reads vs phase1 writes
            *(short8*)(sK + krow * 128 + (kcolb ^ swzK)) = kv;
            *(short8*)(sV + vrow * 64  + (vcolb ^ swzV)) = vv;
            __syncthreads();

            // S = Q K^T (16 q x 32 key), two 16-key halves
            f32x4 sc[2];
            #pragma unroll
            for (int kh = 0; kh < 2; ++kh) {
                short8 kf0 = *(const short8*)(sK + (kh*16 + fr) * 128 +
                                              ((fg*16) ^ rswzK));
                short8 kf1 = *(const short8*)(sK + (kh*16 + fr) * 128 +
                                              ((64 + fg*16) ^ rswzK));
                f32x4 z = {0.f, 0.f, 0.f, 0.f};
                z = __builtin_amdgcn_mfma_f32_16x16x32_bf16(qf0, kf0, z, 0, 0, 0);
                z = __builtin_amdgcn_mfma_f32_16x16x32_bf16(qf1, kf1, z, 0, 0, 0);
                sc[kh] = z;
            }

            const int kb2 = kt * 32;
            const bool full = (kb2 + 31 <= q0);   // wave-uniform: no masking
            #pragma unroll
            for (int r = 0; r < 4; ++r) {
                const int qg = q0 + fg * 4 + r;
                if (full) {
                    sc[0][r] *= 0.125f;
                    sc[1][r] *= 0.125f;
                } else {
                    #pragma unroll
                    for (int kh = 0; kh < 2; ++kh) {
                        const int kgi = kb2 + kh * 16 + fr;
                        sc[kh][r] = (kgi <= qg) ? sc[kh][r] * 0.125f : -1e30f;
                    }
                }
                float mx = fmaxf(sc[0][r], sc[1][r]);
                mx = fmaxf(mx, __shfl_xor(mx, 1, 64));
                mx = fmaxf(mx, __shfl_xor(mx, 2, 64));
                mx = fmaxf(mx, __shfl_xor(mx, 4, 64));
                mx = fmaxf(mx, __shfl_xor(mx, 8, 64));
                if (mx > mrow[r]) {               // rescale only on max bump
                    const float sf = __expf(mrow[r] - mx);
                    srow[r] *= sf;
                    #pragma unroll
                    for (int db = 0; db < 4; ++db) o[db][r] *= sf;
                    mrow[r] = mx;
                }
                const float p0 = __expf(sc[0][r] - mrow[r]);
                const float p1 = __expf(sc[1][r] - mrow[r]);
                srow[r] += p0 + p1;               // deferred reduce
                const int prow = fg * 4 + r;      // prow&3 == r
                *(u16*)(sP + w*1024 + prow*64 + ((fr*2)      ^ (r << 4))) = f2bf(p0);
                *(u16*)(sP + w*1024 + prow*64 + ((32 + fr*2) ^ (r << 4))) = f2bf(p1);
            }

            // sP is per-wave: only wave-local store->load ordering needed.
            // rule-18 pattern: waitcnt + sched_barrier (no block barrier).
            asm volatile("s_waitcnt lgkmcnt(0)" ::: "memory");
            __builtin_amdgcn_sched_barrier(0);

            short8 pf = *(const short8*)(sP + w*1024 + fr*64 + ((fg*16) ^ rswzV));
            #pragma unroll
            for (int db = 0; db < 4; ++db) {
                short8 vf = *(const short8*)(sV + (db*16 + fr) * 64 +
                                             ((fg*16) ^ rswzV));
                o[db] = __builtin_amdgcn_mfma_f32_16x16x32_bf16(pf, vf, o[db], 0, 0, 0);
            }
        }

        // final softmax-denominator reduce (deferred from the tile loop)
        #pragma unroll
        for (int r = 0; r < 4; ++r) {
            float rs = srow[r];
            rs += __shfl_xor(rs, 1, 64);
            rs += __shfl_xor(rs, 2, 64);
            rs += __shfl_xor(rs, 4, 64);
            rs += __shfl_xor(rs, 8, 64);
            const float inv = 1.f / rs;
            #pragma unroll
            for (int db = 0; db < 4; ++db) {
                const int t = q0 + fg * 4 + r;
                att[(size_t)(b * T_SEQ + t) * CDIM + h * 64 + db * 16 + fr] =
                    f2bf(o[db][r] * inv);
            }
        }
    }
}

// ---------------------------------------------------------------------------
// Orchestration. Inputs fp32 (by size), outputs fp32 (y,k,v).
// Workspace (48 MiB, overlapped):
//   [ 0,16M)  q_ws bf16;  wTp overlays after attn
//   [16,32M)  x_bf -> vT bf16 after gemm0
//   [32,48M)  wTa -> attb bf16 after gemm0
// ---------------------------------------------------------------------------
extern "C" void kernel_launch(void* const* d_in, const int* in_sizes, int n_in,
                              void* d_out, int out_size, void* d_ws, size_t ws_size,
                              hipStream_t stream) {
    (void)out_size; (void)ws_size;
    const float *x = nullptr, *w_attn = nullptr, *b_attn = nullptr,
                *w_proj = nullptr, *b_proj = nullptr;
    for (int i = 0; i < n_in; ++i) {
        switch (in_sizes[i]) {
            case 8388608: x      = (const float*)d_in[i]; break;
            case 3145728: w_attn = (const float*)d_in[i]; break;
            case 3072:    b_attn = (const float*)d_in[i]; break;
            case 1048576: w_proj = (const float*)d_in[i]; break;
            case 1024:    b_proj = (const float*)d_in[i]; break;
        }
    }
    if (!x || !w_attn || !b_attn || !w_proj || !b_proj) return;

    float* out = (float*)d_out;
    unsigned char* ws = (unsigned char*)d_ws;

    u16* q_ws = (u16*)(ws);
    u16* wTp  = (u16*)(ws);
    u16* x_bf = (u16*)(ws + 16777216);
    u16* vT   = (u16*)(ws + 16777216);
    u16* wTa  = (u16*)(ws + 33554432);
    u16* attb = (u16*)(ws + 33554432);

    cast_k<<<8192, 256, 0, stream>>>(x, x_bf, 2097152);
    transpose_k<1><<<dim3(96, 32, 1), dim3(32, 8), 0, stream>>>(w_attn, wTa, 1024, 3072);
    gemm_k<0><<<dim3(24, 64), 256, 0, stream>>>(x_bf, wTa, b_attn, out, q_ws, 1024);
    transpose_k<1><<<dim3(2, 128, 32), dim3(32, 8), 0, stream>>>(out + 2 * (size_t)SEC, vT, 4096, 64);
    attn_k<<<dim3(32, 32), 256, 0, stream>>>(q_ws, out + SEC, vT, attb);
    transpose_k<1><<<dim3(32, 32, 1), dim3(32, 8), 0, stream>>>(w_proj, wTp, 1024, 1024);
    gemm_k<1><<<dim3(8, 64), 256, 0, stream>>>(attb, wTp, b_proj, out, nullptr, 1024);
}

// Round 9
// 330.855 us; speedup vs baseline: 1.9828x; 1.2155x over previous
//
#include <hip/hip_runtime.h>
#include <hip/hip_bf16.h>

typedef unsigned short u16;
typedef __attribute__((ext_vector_type(8))) short short8;   // 8 x bf16 (4 VGPR)
typedef __attribute__((ext_vector_type(4))) short s16x4;
typedef __attribute__((ext_vector_type(4))) float f32x4;

#define T_SEQ  4096
#define HEADS  16
#define HDIM   64
#define CDIM   1024
#define MDIM   8192              // B*T
#define HSZ    (T_SEQ * HDIM)    // elems per (b,h) head-plane
#define SEC    8388608           // elems per qkv section = B*T*C

__device__ __forceinline__ u16 f2bf(float f) {
    __hip_bfloat16 h = __float2bfloat16(f);
    u16 u; __builtin_memcpy(&u, &h, 2);
    return u;
}
__device__ __forceinline__ float bf2f(u16 u) {
    unsigned int x = ((unsigned int)u) << 16;
    float f; __builtin_memcpy(&f, &x, 4);
    return f;
}

// ---------------------------------------------------------------------------
// fp32 -> bf16 cast, 4 elems/thread.
// ---------------------------------------------------------------------------
__global__ __launch_bounds__(256) void cast_k(const float* __restrict__ in,
                                              u16* __restrict__ out, int n4) {
    const int i = blockIdx.x * 256 + threadIdx.x;
    if (i < n4) {
        f32x4 v = ((const f32x4*)in)[i];
        s16x4 o;
        #pragma unroll
        for (int j = 0; j < 4; ++j) o[j] = (short)f2bf(v[j]);
        ((s16x4*)out)[i] = o;
    }
}

// ---------------------------------------------------------------------------
// Batched transpose: out[z][c][r] = (bf16)in[z][r][c].  R,C multiples of 32.
// grid (C/32, R/32, Z), block (32,8)
// ---------------------------------------------------------------------------
template <int IN_F32>
__global__ __launch_bounds__(256) void transpose_k(const void* __restrict__ in_,
                                                   u16* __restrict__ out,
                                                   int R, int C) {
    __shared__ u16 tile[32][33];
    const size_t zoff = (size_t)blockIdx.z * R * C;
    const int c0 = blockIdx.x * 32, r0 = blockIdx.y * 32;
    const int tx = threadIdx.x, ty = threadIdx.y;
    #pragma unroll
    for (int i = ty; i < 32; i += 8) {
        const size_t idx = zoff + (size_t)(r0 + i) * C + c0 + tx;
        tile[i][tx] = IN_F32 ? f2bf(((const float*)in_)[idx])
                             : ((const u16*)in_)[idx];
    }
    __syncthreads();
    #pragma unroll
    for (int i = ty; i < 32; i += 8)
        out[zoff + (size_t)(c0 + i) * R + r0 + tx] = tile[tx][i];
}

// ---------------------------------------------------------------------------
// bf16 GEMM: C[m][n] = sum_k A[m][k] * Bt[n][k] + bias[n]   (bias fp32)
//   128x128 tile, BK=64, 4 waves (2x2), 16x16x32 MFMA, XOR-swizzled LDS.
// MODE 0: qkv epilogue -> q->qws (bf16); k/v -> outp fp32 head layout
// MODE 1: proj epilogue -> y row-major fp32
// grid (N/128, MDIM/128), block 256
// ---------------------------------------------------------------------------
template <int MODE>
__global__ __launch_bounds__(256) void gemm_k(const u16* __restrict__ A,
                                              const u16* __restrict__ Bt,
                                              const float* __restrict__ bias,
                                              float* __restrict__ outp,
                                              u16* __restrict__ qws, int K) {
    __shared__ unsigned char sA[16384];   // [128 rows][64 k] bf16, 128B rows
    __shared__ unsigned char sB[16384];
    const int tid  = threadIdx.x;
    const int lane = tid & 63;
    const int w = tid >> 6, wr = w >> 1, wc = w & 1;
    const int m0 = blockIdx.y * 128, n0 = blockIdx.x * 128;
    const int fr = lane & 15, fg = lane >> 4;

    f32x4 acc[4][4] = {};

    const int srow  = tid >> 1;
    const int scolb = (tid & 1) * 64;
    const u16* ga = A  + (size_t)(m0 + srow) * K + (tid & 1) * 32;
    const u16* gb = Bt + (size_t)(n0 + srow) * K + (tid & 1) * 32;
    unsigned char* wAr = sA + srow * 128;
    unsigned char* wBr = sB + srow * 128;
    const int swz  = (srow & 7) << 4;
    const int rswz = (fr & 7) << 4;

    const int nk = K >> 6;
    for (int kt = 0; kt < nk; ++kt) {
        short8 va0 = *(const short8*)(ga + 0);
        short8 va1 = *(const short8*)(ga + 8);
        short8 va2 = *(const short8*)(ga + 16);
        short8 va3 = *(const short8*)(ga + 24);
        short8 vb0 = *(const short8*)(gb + 0);
        short8 vb1 = *(const short8*)(gb + 8);
        short8 vb2 = *(const short8*)(gb + 16);
        short8 vb3 = *(const short8*)(gb + 24);
        ga += 64; gb += 64;
        __syncthreads();
        *(short8*)(wAr + ((scolb +  0) ^ swz)) = va0;
        *(short8*)(wAr + ((scolb + 16) ^ swz)) = va1;
        *(short8*)(wAr + ((scolb + 32) ^ swz)) = va2;
        *(short8*)(wAr + ((scolb + 48) ^ swz)) = va3;
        *(short8*)(wBr + ((scolb +  0) ^ swz)) = vb0;
        *(short8*)(wBr + ((scolb + 16) ^ swz)) = vb1;
        *(short8*)(wBr + ((scolb + 32) ^ swz)) = vb2;
        *(short8*)(wBr + ((scolb + 48) ^ swz)) = vb3;
        __syncthreads();
        #pragma unroll
        for (int kk = 0; kk < 2; ++kk) {
            short8 af[4], bf[4];
            #pragma unroll
            for (int m = 0; m < 4; ++m)
                af[m] = *(const short8*)(sA + (wr*64 + m*16 + fr) * 128 +
                                         ((kk*64 + fg*16) ^ rswz));
            #pragma unroll
            for (int n = 0; n < 4; ++n)
                bf[n] = *(const short8*)(sB + (wc*64 + n*16 + fr) * 128 +
                                         ((kk*64 + fg*16) ^ rswz));
            #pragma unroll
            for (int m = 0; m < 4; ++m)
                #pragma unroll
                for (int n = 0; n < 4; ++n)
                    acc[m][n] = __builtin_amdgcn_mfma_f32_16x16x32_bf16(
                        af[m], bf[n], acc[m][n], 0, 0, 0);
        }
    }

    // epilogue: C/D layout col = lane&15, row = (lane>>4)*4 + reg  [m89]
    #pragma unroll
    for (int n = 0; n < 4; ++n) {
        const int gn = n0 + wc*64 + n*16 + fr;
        const float bn = bias[gn];
        if (MODE == 0) {
            const int s = gn >> 10;               // 0=q 1=k 2=v
            const int c = gn & 1023;
            const int h = c >> 6, d = c & 63;
            if (s == 0) {
                #pragma unroll
                for (int m = 0; m < 4; ++m)
                    #pragma unroll
                    for (int r = 0; r < 4; ++r) {
                        const int gm = m0 + wr*64 + m*16 + fg*4 + r;
                        const int b = gm >> 12, t = gm & 4095;
                        qws[(size_t)((b << 4) + h) * HSZ + (size_t)t * HDIM + d] =
                            f2bf(acc[m][n][r] + bn);
                    }
            } else {
                float* fdst = outp + (size_t)s * SEC;
                #pragma unroll
                for (int m = 0; m < 4; ++m)
                    #pragma unroll
                    for (int r = 0; r < 4; ++r) {
                        const int gm = m0 + wr*64 + m*16 + fg*4 + r;
                        const int b = gm >> 12, t = gm & 4095;
                        fdst[(size_t)((b << 4) + h) * HSZ + (size_t)t * HDIM + d] =
                            acc[m][n][r] + bn;
                    }
            }
        } else {
            #pragma unroll
            for (int m = 0; m < 4; ++m)
                #pragma unroll
                for (int r = 0; r < 4; ++r) {
                    const int gm = m0 + wr*64 + m*16 + fg*4 + r;
                    outp[(size_t)gm * CDIM + gn] = acc[m][n][r] + bn;
                }
        }
    }
}

// ---------------------------------------------------------------------------
// Flash attention fwd (causal), bf16 MFMA, fp32 accum, causal-balanced,
// XCD-locality remapped, ballot-gated defer-max softmax.
//   q: (BH,T,64) bf16   k: (BH,T,64) fp32   vt: (BH,64,T) bf16
//   att out: (B, T, H*64) bf16
// grid 1024 (=8 XCD x 4 bh x 32 pairs), block 256.
// ---------------------------------------------------------------------------
__global__ __launch_bounds__(256) void attn_k(const u16* __restrict__ q,
                                              const float* __restrict__ kk_,
                                              const u16* __restrict__ vt,
                                              u16* __restrict__ att) {
    __shared__ unsigned char sK[4096];   // [32 key][64 d]  128B rows
    __shared__ unsigned char sV[4096];   // [64 d][32 key]  64B rows (V^T tile)
    __shared__ unsigned char sP[4096];   // per-wave [16 q][32 key] 1KB each
    // XCD-aware decode: hw assigns XCD = dispatch_index % 8 (m09 round-robin).
    // Give each XCD 4 whole bh's (all 32 pair-blocks) for K/V/Q L2 locality.
    const int wg  = blockIdx.x;            // 0..1023
    const int xcd = wg & 7;
    const int i   = wg >> 3;               // 0..127
    const int bh  = xcd * 4 + (i >> 5);
    const int pair = i & 31;
    const int tid = threadIdx.x, lane = tid & 63, w = tid >> 6;
    const int fr = lane & 15, fg = lane >> 4;
    const size_t hbase = (size_t)bh * HSZ;

    const int krow = tid >> 3, kcolb = (tid & 7) * 16;
    const int swzK = (krow & 7) << 4;
    const int vrow = tid >> 2, vcolb = (tid & 3) * 16;
    const int swzV = (vrow & 3) << 4;
    const int rswzK = (fr & 7) << 4;
    const int rswzV = (fr & 3) << 4;
    // sP swizzle: fg-dependent bank spread, read-consistent (bits 4-5 only)
    const int rswzP = (((fr & 3) ^ ((fr >> 2) & 3)) << 4);

    const float* gk = kk_ + hbase + (size_t)krow * 64 + (tid & 7) * 8;  // fp32
    const u16*   gv = vt  + hbase + (size_t)vrow * T_SEQ + (tid & 3) * 8;
    const int b = bh >> 4, h = bh & 15;

    #pragma unroll
    for (int ph = 0; ph < 2; ++ph) {
        const int qblk = ph ? 63 - pair : pair;
        const int q0 = qblk * 64 + w * 16;

        short8 qf0 = *(const short8*)(q + hbase + (size_t)(q0 + fr) * 64 + fg * 8);
        short8 qf1 = *(const short8*)(q + hbase + (size_t)(q0 + fr) * 64 + 32 + fg * 8);

        f32x4 o[4] = {};
        float mrow[4] = {-1e30f, -1e30f, -1e30f, -1e30f};
        float srow[4] = {0.f, 0.f, 0.f, 0.f};   // per-lane partial sums

        const int nkt = 2 * (qblk + 1);
        for (int kt = 0; kt < nkt; ++kt) {
            f32x4 ka = *(const f32x4*)(gk + (size_t)kt * 2048);
            f32x4 kb = *(const f32x4*)(gk + (size_t)kt * 2048 + 4);
            short8 kv;
            #pragma unroll
            for (int j = 0; j < 4; ++j) {
                kv[j]     = (short)f2bf(ka[j]);
                kv[4 + j] = (short)f2bf(kb[j]);
            }
            short8 vv = *(const short8*)(gv + kt * 32);
            __syncthreads();   // also orders phase0 LDS reads vs phase1 writes
            *(short8*)(sK + krow * 128 + (kcolb ^ swzK)) = kv;
            *(short8*)(sV + vrow * 64  + (vcolb ^ swzV)) = vv;
            __syncthreads();

            // S = Q K^T (16 q x 32 key), two 16-key halves
            f32x4 sc[2];
            #pragma unroll
            for (int kh = 0; kh < 2; ++kh) {
                short8 kf0 = *(const short8*)(sK + (kh*16 + fr) * 128 +
                                              ((fg*16) ^ rswzK));
                short8 kf1 = *(const short8*)(sK + (kh*16 + fr) * 128 +
                                              ((64 + fg*16) ^ rswzK));
                f32x4 z = {0.f, 0.f, 0.f, 0.f};
                z = __builtin_amdgcn_mfma_f32_16x16x32_bf16(qf0, kf0, z, 0, 0, 0);
                z = __builtin_amdgcn_mfma_f32_16x16x32_bf16(qf1, kf1, z, 0, 0, 0);
                sc[kh] = z;
            }

            const int kb2 = kt * 32;
            const bool full = (kb2 + 31 <= q0);   // wave-uniform: no masking
            #pragma unroll
            for (int r = 0; r < 4; ++r) {
                const int qg = q0 + fg * 4 + r;
                if (full) {
                    sc[0][r] *= 0.125f;
                    sc[1][r] *= 0.125f;
                } else {
                    #pragma unroll
                    for (int kh = 0; kh < 2; ++kh) {
                        const int kgi = kb2 + kh * 16 + fr;
                        sc[kh][r] = (kgi <= qg) ? sc[kh][r] * 0.125f : -1e30f;
                    }
                }
                // ballot-gated defer-max (T13): skip the 4-shfl reduce unless
                // some lane in this row's 16-group exceeds mrow+8.
                const float mx2 = fmaxf(sc[0][r], sc[1][r]);
                const unsigned long long bb = __ballot(mx2 > mrow[r] + 8.f);
                if ((bb >> (fg * 16)) & 0xFFFFull) {
                    float mx = mx2;
                    mx = fmaxf(mx, __shfl_xor(mx, 1, 64));
                    mx = fmaxf(mx, __shfl_xor(mx, 2, 64));
                    mx = fmaxf(mx, __shfl_xor(mx, 4, 64));
                    mx = fmaxf(mx, __shfl_xor(mx, 8, 64));
                    const float sf = __expf(mrow[r] - mx);  // -1e30 -> sf=0
                    srow[r] *= sf;
                    #pragma unroll
                    for (int db = 0; db < 4; ++db) o[db][r] *= sf;
                    mrow[r] = mx;
                }
                const float p0 = __expf(sc[0][r] - mrow[r]);  // bounded e^8
                const float p1 = __expf(sc[1][r] - mrow[r]);
                srow[r] += p0 + p1;               // deferred reduce
                const int prow = fg * 4 + r;      // row this lane-group owns
                const int sw = ((r ^ fg) & 3) << 4;   // = swzP(prow)
                *(u16*)(sP + w*1024 + prow*64 + ((fr*2)      ^ sw)) = f2bf(p0);
                *(u16*)(sP + w*1024 + prow*64 + ((32 + fr*2) ^ sw)) = f2bf(p1);
            }

            // sP is per-wave: wave-local store->load ordering only (rule 18).
            asm volatile("s_waitcnt lgkmcnt(0)" ::: "memory");
            __builtin_amdgcn_sched_barrier(0);

            short8 pf = *(const short8*)(sP + w*1024 + fr*64 + ((fg*16) ^ rswzP));
            #pragma unroll
            for (int db = 0; db < 4; ++db) {
                short8 vf = *(const short8*)(sV + (db*16 + fr) * 64 +
                                             ((fg*16) ^ rswzV));
                o[db] = __builtin_amdgcn_mfma_f32_16x16x32_bf16(pf, vf, o[db], 0, 0, 0);
            }
        }

        // final softmax-denominator reduce (deferred from the tile loop)
        #pragma unroll
        for (int r = 0; r < 4; ++r) {
            float rs = srow[r];
            rs += __shfl_xor(rs, 1, 64);
            rs += __shfl_xor(rs, 2, 64);
            rs += __shfl_xor(rs, 4, 64);
            rs += __shfl_xor(rs, 8, 64);
            const float inv = 1.f / rs;
            #pragma unroll
            for (int db = 0; db < 4; ++db) {
                const int t = q0 + fg * 4 + r;
                att[(size_t)(b * T_SEQ + t) * CDIM + h * 64 + db * 16 + fr] =
                    f2bf(o[db][r] * inv);
            }
        }
    }
}

// ---------------------------------------------------------------------------
// Orchestration. Inputs fp32 (by size), outputs fp32 (y,k,v).
// Workspace (48 MiB, overlapped):
//   [ 0,16M)  q_ws bf16;  wTp overlays after attn
//   [16,32M)  x_bf -> vT bf16 after gemm0
//   [32,48M)  wTa -> attb bf16 after gemm0
// ---------------------------------------------------------------------------
extern "C" void kernel_launch(void* const* d_in, const int* in_sizes, int n_in,
                              void* d_out, int out_size, void* d_ws, size_t ws_size,
                              hipStream_t stream) {
    (void)out_size; (void)ws_size;
    const float *x = nullptr, *w_attn = nullptr, *b_attn = nullptr,
                *w_proj = nullptr, *b_proj = nullptr;
    for (int i = 0; i < n_in; ++i) {
        switch (in_sizes[i]) {
            case 8388608: x      = (const float*)d_in[i]; break;
            case 3145728: w_attn = (const float*)d_in[i]; break;
            case 3072:    b_attn = (const float*)d_in[i]; break;
            case 1048576: w_proj = (const float*)d_in[i]; break;
            case 1024:    b_proj = (const float*)d_in[i]; break;
        }
    }
    if (!x || !w_attn || !b_attn || !w_proj || !b_proj) return;

    float* out = (float*)d_out;
    unsigned char* ws = (unsigned char*)d_ws;

    u16* q_ws = (u16*)(ws);
    u16* wTp  = (u16*)(ws);
    u16* x_bf = (u16*)(ws + 16777216);
    u16* vT   = (u16*)(ws + 16777216);
    u16* wTa  = (u16*)(ws + 33554432);
    u16* attb = (u16*)(ws + 33554432);

    cast_k<<<8192, 256, 0, stream>>>(x, x_bf, 2097152);
    transpose_k<1><<<dim3(96, 32, 1), dim3(32, 8), 0, stream>>>(w_attn, wTa, 1024, 3072);
    gemm_k<0><<<dim3(24, 64), 256, 0, stream>>>(x_bf, wTa, b_attn, out, q_ws, 1024);
    transpose_k<1><<<dim3(2, 128, 32), dim3(32, 8), 0, stream>>>(out + 2 * (size_t)SEC, vT, 4096, 64);
    attn_k<<<1024, 256, 0, stream>>>(q_ws, out + SEC, vT, attb);
    transpose_k<1><<<dim3(32, 32, 1), dim3(32, 8), 0, stream>>>(w_proj, wTp, 1024, 1024);
    gemm_k<1><<<dim3(8, 64), 256, 0, stream>>>(attb, wTp, b_proj, out, nullptr, 1024);
}